// Round 8
// baseline (164.460 us; speedup 1.0000x reference)
//
#include <hip/hip_runtime.h>
#include <hip/hip_bf16.h>
#include <math.h>

#define N_TOKENS 8192
#define DIM      512
#define N_TOOLS  50
#define PARAM_DIM 256
#define N_ROWBLK (N_TOKENS / 64)   // 128 (64-token histogram granules)
#define MAX_BATCHES 192            // BM=64 batches: <= 50 + 128 = 178
#define LDSS 72   // LDS inner stride in bf16 elems (144 B -> 2-way bank aliasing max, free)

typedef float  f32x4 __attribute__((ext_vector_type(4)));
typedef short  s16x8 __attribute__((ext_vector_type(8)));
typedef short  s16x4 __attribute__((ext_vector_type(4)));

// ---- workspace layout (ints) ----
#define WS_IDX     0        // 8192  token -> expert
#define WS_HIST    8192     // 128*50 per-rowblock histograms
#define WS_PHIST   14592    // 128*50 exclusive block-prefix per expert
#define WS_OFFSETS 20992    // 64
#define WS_COUNTS  21056    // 64
#define WS_ORDER   21120    // 8192
#define WS_BE      29312    // 192
#define WS_BM0     29504    // 192
#define WS_NB      29696    // 1
#define WS_XH      32768                 // x hi bf16: 2,097,152 ints
#define WS_XL      (WS_XH + 2097152)     // x lo bf16
#define WS_EWH     (WS_XL + 2097152)     // expert_w bf16: 6,553,600 ints
#define WS_PWH     (WS_EWH + 6553600)    // param_w bf16: 65,536 ints

// cvt ranges in float4 units
#define X4   1048576   // 8192*512/4
#define EW4  3276800   // 50*512*512/4
#define PW4  32768     // 256*512/4
#define TOT4 (X4 + EW4 + PW4)   // 4,358,144 = 17024 * 256

__device__ inline float bf2f(short s) {
    return __uint_as_float(((unsigned)(unsigned short)s) << 16);
}

__device__ inline s16x4 pk4(float a, float b, float c, float d) {
    __hip_bfloat162 p0 = __float22bfloat162_rn(make_float2(a, b));
    __hip_bfloat162 p1 = __float22bfloat162_rn(make_float2(c, d));
    union { __hip_bfloat162 h; short2 s; } u0, u1;
    u0.h = p0; u1.h = p1;
    s16x4 r; r[0] = u0.s.x; r[1] = u0.s.y; r[2] = u1.s.x; r[3] = u1.s.y;
    return r;
}

// ---------------- pre-convert: x -> (hi,lo) bf16; expert_w, param_w -> bf16 ----------------
__global__ __launch_bounds__(256) void cvt_all(const float* __restrict__ x,
                                               const float* __restrict__ ew,
                                               const float* __restrict__ pw,
                                               short* __restrict__ xh,
                                               short* __restrict__ xl,
                                               short* __restrict__ ewh,
                                               short* __restrict__ pwh) {
    size_t u = (size_t)blockIdx.x * 256 + threadIdx.x;
    if (u < X4) {
        size_t i = u * 4;
        float4 v = *(const float4*)&x[i];
        s16x4 h = pk4(v.x, v.y, v.z, v.w);
        s16x4 l = pk4(v.x - bf2f(h[0]), v.y - bf2f(h[1]),
                      v.z - bf2f(h[2]), v.w - bf2f(h[3]));
        *(s16x4*)&xh[i] = h;
        *(s16x4*)&xl[i] = l;
    } else if (u < X4 + EW4) {
        size_t i = (u - X4) * 4;
        float4 v = *(const float4*)&ew[i];
        *(s16x4*)&ewh[i] = pk4(v.x, v.y, v.z, v.w);
    } else {
        size_t i = (u - X4 - EW4) * 4;
        float4 v = *(const float4*)&pw[i];
        *(s16x4*)&pwh[i] = pk4(v.x, v.y, v.z, v.w);
    }
}

// ---------------- fused head: params (tiles 0-3) + logits/softmax/argmax (tile 4) ----------------
// grid (5, 128), block 256 (4 waves). BM=64, BK=64. A-frags direct from global (no A LDS).
// B-only LDS (Bs; + Bl for the split-bf16 logits tile). Register prefetch one K-tile ahead.
__global__ __launch_bounds__(256) void head_mfma(const short* __restrict__ xh,
                                                 const short* __restrict__ xl,
                                                 const short* __restrict__ pwh,
                                                 const float* __restrict__ pb,
                                                 const float* __restrict__ rw,
                                                 const float* __restrict__ rb,
                                                 float* __restrict__ out_params,
                                                 float* __restrict__ probs,
                                                 float* __restrict__ out_idx,
                                                 int* __restrict__ idx_i,
                                                 int* __restrict__ hist) {
    int r0 = blockIdx.y * 64;
    bool isl = (blockIdx.x == 4);
    int c0 = isl ? 0 : blockIdx.x * 64;

    __shared__ short Bs[64 * LDSS];
    __shared__ short Bl[64 * LDSS];   // logits tile only
    __shared__ int rowcol[64];

    int tid = threadIdx.x;
    int wv = tid >> 6;
    int lane = tid & 63;
    int fm = lane & 15;
    int q = lane >> 4;

    // A direct: this lane's fragment row
    const short* aph = xh + (size_t)(r0 + wv * 16 + fm) * DIM + q * 8;
    const short* apl = xl + (size_t)(r0 + wv * 16 + fm) * DIM + q * 8;

    f32x4 acc[4] = {{0.f, 0.f, 0.f, 0.f}, {0.f, 0.f, 0.f, 0.f},
                    {0.f, 0.f, 0.f, 0.f}, {0.f, 0.f, 0.f, 0.f}};
    const s16x8 z8 = {0, 0, 0, 0, 0, 0, 0, 0};

    if (!isl) {
        // ---- params tile: bf16 B from pwh ----
        int col[2], g[2];
        const short* bptr[2];
#pragma unroll
        for (int i = 0; i < 2; ++i) {
            int u = i * 256 + tid;
            col[i] = u >> 3; g[i] = u & 7;
            bptr[i] = pwh + (size_t)(c0 + col[i]) * DIM + g[i] * 8;
        }
        s16x8 bpre[2];
#pragma unroll
        for (int i = 0; i < 2; ++i) bpre[i] = *(const s16x8*)bptr[i];
        s16x8 a0 = *(const s16x8*)aph;
        s16x8 a1 = *(const s16x8*)(aph + 32);

        for (int k0 = 0; k0 < DIM; k0 += 64) {
#pragma unroll
            for (int i = 0; i < 2; ++i)
                *(s16x8*)&Bs[col[i] * LDSS + g[i] * 8] = bpre[i];
            __syncthreads();

            int kn = k0 + 64;
            s16x8 a0n = z8, a1n = z8;
            if (kn < DIM) {
#pragma unroll
                for (int i = 0; i < 2; ++i) bpre[i] = *(const s16x8*)(bptr[i] + kn);
                a0n = *(const s16x8*)(aph + kn);
                a1n = *(const s16x8*)(aph + kn + 32);
            }

#pragma unroll
            for (int kk = 0; kk < 64; kk += 32) {
                s16x8 a = kk ? a1 : a0;
#pragma unroll
                for (int n = 0; n < 4; ++n) {
                    s16x8 b = *(const s16x8*)&Bs[(n * 16 + fm) * LDSS + kk + q * 8];
                    acc[n] = __builtin_amdgcn_mfma_f32_16x16x32_bf16(a, b, acc[n], 0, 0, 0);
                }
            }
            __syncthreads();
            a0 = a0n; a1 = a1n;
        }

        float bias[4];
#pragma unroll
        for (int n = 0; n < 4; ++n) bias[n] = pb[c0 + n * 16 + fm];
#pragma unroll
        for (int r = 0; r < 4; ++r) {
            int row = r0 + wv * 16 + q * 4 + r;
            float* op = out_params + (size_t)row * PARAM_DIM + c0;
#pragma unroll
            for (int n = 0; n < 4; ++n) op[n * 16 + fm] = acc[n][r] + bias[n];
        }
    } else {
        // ---- logits tile: split-bf16 (x=hi+lo, w=hi+lo; 3 MFMAs) ----
        int col[4], g[4];
        const float* bptr[4];
#pragma unroll
        for (int i = 0; i < 4; ++i) {
            int u = i * 256 + tid;
            col[i] = u >> 4; g[i] = u & 15;
            bptr[i] = rw + (size_t)col[i] * DIM + g[i] * 4;
        }
        float4 bpre[4];
#pragma unroll
        for (int i = 0; i < 4; ++i) {
            float4 v = {0.f, 0.f, 0.f, 0.f};
            if (col[i] < N_TOOLS) v = *(const float4*)bptr[i];
            bpre[i] = v;
        }
        s16x8 a0h = *(const s16x8*)aph;
        s16x8 a1h = *(const s16x8*)(aph + 32);
        s16x8 a0l = *(const s16x8*)apl;
        s16x8 a1l = *(const s16x8*)(apl + 32);

        for (int k0 = 0; k0 < DIM; k0 += 64) {
#pragma unroll
            for (int i = 0; i < 4; ++i) {
                float4 v = bpre[i];
                s16x4 h = pk4(v.x, v.y, v.z, v.w);
                *(s16x4*)&Bs[col[i] * LDSS + g[i] * 4] = h;
                s16x4 l = pk4(v.x - bf2f(h[0]), v.y - bf2f(h[1]),
                              v.z - bf2f(h[2]), v.w - bf2f(h[3]));
                *(s16x4*)&Bl[col[i] * LDSS + g[i] * 4] = l;
            }
            __syncthreads();

            int kn = k0 + 64;
            s16x8 a0hn = z8, a1hn = z8, a0ln = z8, a1ln = z8;
            if (kn < DIM) {
#pragma unroll
                for (int i = 0; i < 4; ++i) {
                    float4 v = {0.f, 0.f, 0.f, 0.f};
                    if (col[i] < N_TOOLS) v = *(const float4*)(bptr[i] + kn);
                    bpre[i] = v;
                }
                a0hn = *(const s16x8*)(aph + kn);
                a1hn = *(const s16x8*)(aph + kn + 32);
                a0ln = *(const s16x8*)(apl + kn);
                a1ln = *(const s16x8*)(apl + kn + 32);
            }

#pragma unroll
            for (int kk = 0; kk < 64; kk += 32) {
                s16x8 ah = kk ? a1h : a0h;
                s16x8 al = kk ? a1l : a0l;
#pragma unroll
                for (int n = 0; n < 4; ++n) {
                    int bo = (n * 16 + fm) * LDSS + kk + q * 8;
                    s16x8 b  = *(const s16x8*)&Bs[bo];
                    s16x8 bl = *(const s16x8*)&Bl[bo];
                    acc[n] = __builtin_amdgcn_mfma_f32_16x16x32_bf16(ah, b,  acc[n], 0, 0, 0);
                    acc[n] = __builtin_amdgcn_mfma_f32_16x16x32_bf16(ah, bl, acc[n], 0, 0, 0);
                    acc[n] = __builtin_amdgcn_mfma_f32_16x16x32_bf16(al, b,  acc[n], 0, 0, 0);
                }
            }
            __syncthreads();
            a0h = a0hn; a1h = a1hn; a0l = a0ln; a1l = a1ln;
        }

        float rbv[4];
#pragma unroll
        for (int n = 0; n < 4; ++n) {
            int c = n * 16 + fm;
            rbv[n] = (c < N_TOOLS) ? rb[c] : 0.f;
        }
#pragma unroll
        for (int rr = 0; rr < 4; ++rr) {
            int row_l = wv * 16 + q * 4 + rr;
            int row = r0 + row_l;
            float v[4];
            float vmax = -INFINITY; int vcol = N_TOOLS;
#pragma unroll
            for (int n = 0; n < 4; ++n) {
                int c = n * 16 + fm;
                v[n] = acc[n][rr] + rbv[n];
                if (c < N_TOOLS && v[n] > vmax) { vmax = v[n]; vcol = c; }
            }
#pragma unroll
            for (int s = 1; s < 16; s <<= 1) {
                float om = __shfl_xor(vmax, s, 64);
                int   oc = __shfl_xor(vcol, s, 64);
                if (om > vmax || (om == vmax && oc < vcol)) { vmax = om; vcol = oc; }
            }
            float e[4]; float esum = 0.f;
#pragma unroll
            for (int n = 0; n < 4; ++n) {
                int c = n * 16 + fm;
                e[n] = (c < N_TOOLS) ? expf(v[n] - vmax) : 0.f;
                esum += e[n];
            }
#pragma unroll
            for (int s = 1; s < 16; s <<= 1) esum += __shfl_xor(esum, s, 64);
            float inv = 1.f / esum;
#pragma unroll
            for (int n = 0; n < 4; ++n) {
                int c = n * 16 + fm;
                if (c < N_TOOLS) probs[(size_t)row * N_TOOLS + c] = e[n] * inv;
            }
            if (fm == 0) {
                out_idx[row] = (float)vcol;
                idx_i[row] = vcol;
                rowcol[row_l] = vcol;
            }
        }
        __syncthreads();
        if (wv == 0) {
            int myc = rowcol[lane];
            int cnt = 0;
            for (int e2 = 0; e2 < N_TOOLS; ++e2) {
                unsigned long long m = __ballot(myc == e2);
                if (lane == e2) cnt = __popcll(m);
            }
            if (lane < N_TOOLS) hist[blockIdx.y * N_TOOLS + lane] = cnt;
        }
    }
}

// ---------------- fused scan: per-expert block-prefix + offsets + batch table ----------------
// single block, 1024 threads (16 waves). Batch granule = 64 tokens (BM=64).
__global__ __launch_bounds__(1024) void scan_all(const int* __restrict__ hist,
                                                 int* __restrict__ phist,
                                                 int* __restrict__ counts,
                                                 int* __restrict__ offsets,
                                                 int* __restrict__ batch_e,
                                                 int* __restrict__ batch_m0,
                                                 int* __restrict__ nb_out) {
    __shared__ int cnt_s[64];
    int l = threadIdx.x & 63;
    int w = threadIdx.x >> 6;   // 16 waves

    for (int e = w; e < N_TOOLS; e += 16) {
        int v0 = hist[l * N_TOOLS + e];
        int v1 = hist[(64 + l) * N_TOOLS + e];
        int s0 = v0;
#pragma unroll
        for (int s = 1; s < 64; s <<= 1) {
            int t = __shfl_up(s0, s, 64);
            if (l >= s) s0 += t;
        }
        int tot0 = __shfl(s0, 63, 64);
        int s1 = v1;
#pragma unroll
        for (int s = 1; s < 64; s <<= 1) {
            int t = __shfl_up(s1, s, 64);
            if (l >= s) s1 += t;
        }
        s1 += tot0;
        phist[l * N_TOOLS + e] = s0 - v0;
        phist[(64 + l) * N_TOOLS + e] = s1 - v1;
        if (l == 63) cnt_s[e] = s1;
    }
    __syncthreads();

    if (w == 0) {
        int c = (l < N_TOOLS) ? cnt_s[l] : 0;
        int pre = c;
#pragma unroll
        for (int s = 1; s < 64; s <<= 1) {
            int v = __shfl_up(pre, s, 64);
            if (l >= s) pre += v;
        }
        if (l < N_TOOLS) { offsets[l] = pre - c; counts[l] = c; }

        int nb_i = (l < N_TOOLS) ? (c + 63) >> 6 : 0;
        int pre2 = nb_i;
#pragma unroll
        for (int s = 1; s < 64; s <<= 1) {
            int v = __shfl_up(pre2, s, 64);
            if (l >= s) pre2 += v;
        }
        int bstart = pre2 - nb_i;
        for (int b = 0; b < nb_i; ++b) {
            batch_e[bstart + b] = l;
            batch_m0[bstart + b] = b * 64;
        }
        if (l == 63) nb_out[0] = pre2;
    }
}

// ---------------- reorder: deterministic slot per token (no atomics) ----------------
__global__ void reorder_kernel(const int* __restrict__ idx_i,
                               const int* __restrict__ offsets,
                               const int* __restrict__ phist,
                               int* __restrict__ order) {
    int b = blockIdx.x;
    int lane = threadIdx.x;
    int t = b * 64 + lane;
    int e = idx_i[t];
    unsigned long long lt = (1ull << lane) - 1ull;
    int rank = 0;
    for (int ex = 0; ex < N_TOOLS; ++ex) {
        unsigned long long m = __ballot(e == ex);
        if (e == ex) rank = __popcll(m & lt);
    }
    order[offsets[e] + phist[b * N_TOOLS + e] + rank] = t;
}

// ---------------- adapted: grouped bf16 MFMA GEMM, BM=64 BN=128 BK=64 ----------------
// grid (4, MAX_BATCHES), block 256 (4 waves). A-frags gathered direct from global via toks;
// B-only LDS from pre-converted bf16 expert weights; register prefetch one K-tile ahead.
__global__ __launch_bounds__(256) void adapted_mfma(const short* __restrict__ xh,
                                                    const short* __restrict__ ewh,
                                                    const float* __restrict__ eb,
                                                    const int* __restrict__ order,
                                                    const int* __restrict__ batch_e,
                                                    const int* __restrict__ batch_m0,
                                                    const int* __restrict__ nb_ptr,
                                                    const int* __restrict__ offsets,
                                                    const int* __restrict__ counts,
                                                    float* __restrict__ out) {
    int b = blockIdx.y;
    if (b >= nb_ptr[0]) return;
    int e = batch_e[b];
    int m0 = batch_m0[b];
    int c0 = blockIdx.x * 128;
    int start = offsets[e] + m0;
    int len = counts[e] - m0;
    if (len > 64) len = 64;

    __shared__ short Bs[128 * LDSS];
    __shared__ int toks[64];

    int tid = threadIdx.x;
    if (tid < 64) toks[tid] = (tid < len) ? order[start + tid] : -1;
    __syncthreads();

    int wv = tid >> 6;
    int lane = tid & 63;
    int fm = lane & 15;
    int q = lane >> 4;

    const short* Wb = ewh + (size_t)e * DIM * DIM;

    // B staging: 128 cols x 8 granules (16B bf16) = 1024 units, 4/thread
    int col[4], g[4];
    const short* bptr[4];
#pragma unroll
    for (int i = 0; i < 4; ++i) {
        int u = i * 256 + tid;
        col[i] = u >> 3; g[i] = u & 7;
        bptr[i] = Wb + (size_t)(c0 + col[i]) * DIM + g[i] * 8;
    }

    // A direct: this lane's fragment row (invalid rows read row 0, never written back)
    int tok = toks[wv * 16 + fm];
    const short* aph = xh + (size_t)(tok >= 0 ? tok : 0) * DIM + q * 8;

    f32x4 acc[8];
#pragma unroll
    for (int n = 0; n < 8; ++n) acc[n] = {0.f, 0.f, 0.f, 0.f};
    const s16x8 z8 = {0, 0, 0, 0, 0, 0, 0, 0};

    s16x8 bpre[4];
#pragma unroll
    for (int i = 0; i < 4; ++i) bpre[i] = *(const s16x8*)bptr[i];
    s16x8 a0 = *(const s16x8*)aph;
    s16x8 a1 = *(const s16x8*)(aph + 32);

    for (int k0 = 0; k0 < DIM; k0 += 64) {
#pragma unroll
        for (int i = 0; i < 4; ++i)
            *(s16x8*)&Bs[col[i] * LDSS + g[i] * 8] = bpre[i];
        __syncthreads();

        int kn = k0 + 64;
        s16x8 a0n = z8, a1n = z8;
        if (kn < DIM) {
#pragma unroll
            for (int i = 0; i < 4; ++i) bpre[i] = *(const s16x8*)(bptr[i] + kn);
            a0n = *(const s16x8*)(aph + kn);
            a1n = *(const s16x8*)(aph + kn + 32);
        }

#pragma unroll
        for (int kk = 0; kk < 64; kk += 32) {
            s16x8 a = kk ? a1 : a0;
#pragma unroll
            for (int n = 0; n < 8; ++n) {
                s16x8 bf = *(const s16x8*)&Bs[(n * 16 + fm) * LDSS + kk + q * 8];
                acc[n] = __builtin_amdgcn_mfma_f32_16x16x32_bf16(a, bf, acc[n], 0, 0, 0);
            }
        }
        __syncthreads();
        a0 = a0n; a1 = a1n;
    }

    float bias[8];
#pragma unroll
    for (int n = 0; n < 8; ++n) bias[n] = eb[(size_t)e * DIM + c0 + n * 16 + fm];

#pragma unroll
    for (int r = 0; r < 4; ++r) {
        int row_l = wv * 16 + q * 4 + r;
        int tk = toks[row_l];
        if (tk < 0) continue;
        float* op = out + (size_t)tk * DIM + c0;
#pragma unroll
        for (int n = 0; n < 8; ++n) op[n * 16 + fm] = acc[n][r] + bias[n];
    }
}

extern "C" void kernel_launch(void* const* d_in, const int* in_sizes, int n_in,
                              void* d_out, int out_size, void* d_ws, size_t ws_size,
                              hipStream_t stream) {
    const float* x        = (const float*)d_in[0];
    const float* router_w = (const float*)d_in[1];
    const float* router_b = (const float*)d_in[2];
    const float* expert_w = (const float*)d_in[3];
    const float* expert_b = (const float*)d_in[4];
    const float* param_w  = (const float*)d_in[5];
    const float* param_b  = (const float*)d_in[6];

    float* out = (float*)d_out;
    float* out_idx     = out;                                  // 8192
    float* out_probs   = out + N_TOKENS;                       // 409600
    float* out_adapted = out + N_TOKENS + N_TOKENS * N_TOOLS;  // 4194304
    float* out_params  = out_adapted + (size_t)N_TOKENS * DIM; // 2097152

    int* ws = (int*)d_ws;
    int* ws_idx     = ws + WS_IDX;
    int* ws_hist    = ws + WS_HIST;
    int* ws_phist   = ws + WS_PHIST;
    int* ws_offsets = ws + WS_OFFSETS;
    int* ws_counts  = ws + WS_COUNTS;
    int* ws_order   = ws + WS_ORDER;
    int* ws_be      = ws + WS_BE;
    int* ws_bm0     = ws + WS_BM0;
    int* ws_nb      = ws + WS_NB;
    short* ws_xh    = (short*)(ws + WS_XH);
    short* ws_xl    = (short*)(ws + WS_XL);
    short* ws_ewh   = (short*)(ws + WS_EWH);
    short* ws_pwh   = (short*)(ws + WS_PWH);

    cvt_all<<<TOT4 / 256, 256, 0, stream>>>(x, expert_w, param_w,
                                            ws_xh, ws_xl, ws_ewh, ws_pwh);

    head_mfma<<<dim3(5, N_ROWBLK), 256, 0, stream>>>(ws_xh, ws_xl, ws_pwh, param_b,
                                                     router_w, router_b,
                                                     out_params, out_probs,
                                                     out_idx, ws_idx, ws_hist);

    scan_all<<<1, 1024, 0, stream>>>(ws_hist, ws_phist, ws_counts, ws_offsets,
                                     ws_be, ws_bm0, ws_nb);

    reorder_kernel<<<N_ROWBLK, 64, 0, stream>>>(ws_idx, ws_offsets, ws_phist, ws_order);

    adapted_mfma<<<dim3(4, MAX_BATCHES), 256, 0, stream>>>(ws_xh, ws_ewh, expert_b,
                                                           ws_order, ws_be, ws_bm0, ws_nb,
                                                           ws_offsets, ws_counts, out_adapted);
}